// Round 1
// baseline (608.122 us; speedup 1.0000x reference)
//
#include <hip/hip_runtime.h>
#include <cstdint>
#include <cstddef>

typedef __bf16 bf16_t;
typedef __attribute__((ext_vector_type(8))) __bf16 bf16x8;
typedef __attribute__((ext_vector_type(4))) __bf16 bf16x4;
typedef __attribute__((ext_vector_type(4))) float floatx4;

// ---------------------------------------------------------------------------
// async global->LDS, 16B per lane. LDS dest is wave-uniform base + lane*16.
// ---------------------------------------------------------------------------
__device__ __forceinline__ void async_copy16(const void* g, void* l) {
  __builtin_amdgcn_global_load_lds(
      (const __attribute__((address_space(1))) void*)g,
      (__attribute__((address_space(3))) void*)l,
      16, 0, 0);
}

// ---------------------------------------------------------------------------
// NT GEMM: C[M,N] = alpha * A[M,K] * B[N,K]^T.  M,N % 128 == 0, K % 32 == 0.
// 128x128 block tile, BK=32, 4 waves of 64x64, 16x16x32 bf16 MFMA.
// ---------------------------------------------------------------------------
template <int OUT_BF16>
__global__ __launch_bounds__(256, 2)
void gemm_nt_kernel(const bf16_t* __restrict__ A, const bf16_t* __restrict__ B,
                    void* __restrict__ C, int M, int N, int K, float alpha) {
  __shared__ __align__(16) bf16_t As[128 * 32];
  __shared__ __align__(16) bf16_t Bs[128 * 32];

  const int tid   = threadIdx.x;
  const int lane  = tid & 63;
  const int wave  = tid >> 6;
  const int waveM = wave >> 1;  // 0..1
  const int waveN = wave & 1;   // 0..1

  const int bM = blockIdx.y * 128;
  const int bN = blockIdx.x * 128;

  // staging: chunk = 16 rows (1 KB). wave handles chunks (2*wave, 2*wave+1).
  const int ldRow = lane >> 2;        // row within chunk
  const int ldCol = (lane & 3) * 8;   // bf16 col offset (0,8,16,24)
  const int c0 = wave * 2, c1 = wave * 2 + 1;

  const bf16_t* Ag0 = A + (size_t)(bM + c0 * 16 + ldRow) * K + ldCol;
  const bf16_t* Ag1 = A + (size_t)(bM + c1 * 16 + ldRow) * K + ldCol;
  const bf16_t* Bg0 = B + (size_t)(bN + c0 * 16 + ldRow) * K + ldCol;
  const bf16_t* Bg1 = B + (size_t)(bN + c1 * 16 + ldRow) * K + ldCol;
  bf16_t* AsD0 = &As[c0 * 512];
  bf16_t* AsD1 = &As[c1 * 512];
  bf16_t* BsD0 = &Bs[c0 * 512];
  bf16_t* BsD1 = &Bs[c1 * 512];

  // fragment read indices: lane l holds X[l&15][ (l>>4)*8 + j ]
  const int fRow = lane & 15;
  const int fK   = (lane >> 4) * 8;

  floatx4 acc[4][4];
#pragma unroll
  for (int i = 0; i < 4; ++i)
#pragma unroll
    for (int j = 0; j < 4; ++j) acc[i][j] = (floatx4)0.0f;

  for (int k0 = 0; k0 < K; k0 += 32) {
    async_copy16(Ag0 + k0, AsD0);
    async_copy16(Ag1 + k0, AsD1);
    async_copy16(Bg0 + k0, BsD0);
    async_copy16(Bg1 + k0, BsD1);
    __syncthreads();  // drains vmcnt for the async LDS writes

    bf16x8 af[4], bfr[4];
#pragma unroll
    for (int mt = 0; mt < 4; ++mt)
      af[mt] = *(const bf16x8*)&As[(waveM * 64 + mt * 16 + fRow) * 32 + fK];
#pragma unroll
    for (int nt = 0; nt < 4; ++nt)
      bfr[nt] = *(const bf16x8*)&Bs[(waveN * 64 + nt * 16 + fRow) * 32 + fK];
#pragma unroll
    for (int mt = 0; mt < 4; ++mt)
#pragma unroll
      for (int nt = 0; nt < 4; ++nt)
        acc[mt][nt] = __builtin_amdgcn_mfma_f32_16x16x32_bf16(
            af[mt], bfr[nt], acc[mt][nt], 0, 0, 0);
    __syncthreads();  // all waves done reading before next staging overwrites
  }

  // epilogue: C/D layout col = lane&15, row = (lane>>4)*4 + reg
  const int rBase = bM + waveM * 64 + (lane >> 4) * 4;
  const int cBase = bN + waveN * 64 + (lane & 15);
#pragma unroll
  for (int mt = 0; mt < 4; ++mt) {
#pragma unroll
    for (int nt = 0; nt < 4; ++nt) {
#pragma unroll
      for (int r = 0; r < 4; ++r) {
        const size_t idx = (size_t)(rBase + mt * 16 + r) * N + (cBase + nt * 16);
        const float v = acc[mt][nt][r] * alpha;
        if (OUT_BF16)
          ((bf16_t*)C)[idx] = (bf16_t)v;
        else
          ((float*)C)[idx] = v;
      }
    }
  }
}

// ---------------------------------------------------------------------------
// fp32 -> bf16 convert, 4 elems/thread
// ---------------------------------------------------------------------------
__global__ void cvt_kernel(const float* __restrict__ in, bf16_t* __restrict__ out,
                           int n) {
  const int i = (blockIdx.x * 256 + threadIdx.x) * 4;
  if (i >= n) return;
  const float4 v = *(const float4*)(in + i);
  bf16x4 o;
  o[0] = (bf16_t)v.x; o[1] = (bf16_t)v.y; o[2] = (bf16_t)v.z; o[3] = (bf16_t)v.w;
  *(bf16x4*)(out + i) = o;
}

// ---------------------------------------------------------------------------
// row softmax over 8192 bf16 logits, in place; writes bf16(exp(s-m)/l)
// one block (256 threads) per row, 32 elems/thread in registers
// ---------------------------------------------------------------------------
__global__ __launch_bounds__(256)
void softmax_kernel(bf16_t* __restrict__ S) {
  const int tid  = threadIdx.x;
  const int lane = tid & 63;
  const int wave = tid >> 6;
  bf16x8* p8 = (bf16x8*)(S + (size_t)blockIdx.x * 8192);
  __shared__ float red[8];

  float vals[32];
#pragma unroll
  for (int c = 0; c < 4; ++c) {
    const bf16x8 ch = p8[c * 256 + tid];
#pragma unroll
    for (int j = 0; j < 8; ++j) vals[c * 8 + j] = (float)ch[j];
  }

  float m = -1e30f;
#pragma unroll
  for (int i = 0; i < 32; ++i) m = fmaxf(m, vals[i]);
#pragma unroll
  for (int off = 32; off >= 1; off >>= 1) m = fmaxf(m, __shfl_xor(m, off, 64));
  if (lane == 0) red[wave] = m;
  __syncthreads();
  m = fmaxf(fmaxf(red[0], red[1]), fmaxf(red[2], red[3]));

  float s = 0.0f;
#pragma unroll
  for (int i = 0; i < 32; ++i) {
    vals[i] = __expf(vals[i] - m);
    s += vals[i];
  }
#pragma unroll
  for (int off = 32; off >= 1; off >>= 1) s += __shfl_xor(s, off, 64);
  if (lane == 0) red[4 + wave] = s;
  __syncthreads();
  const float inv = 1.0f / (red[4] + red[5] + red[6] + red[7]);

#pragma unroll
  for (int c = 0; c < 4; ++c) {
    bf16x8 o;
#pragma unroll
    for (int j = 0; j < 8; ++j) o[j] = (bf16_t)(vals[c * 8 + j] * inv);
    p8[c * 256 + tid] = o;
  }
}

// ---------------------------------------------------------------------------
// launch
// ---------------------------------------------------------------------------
extern "C" void kernel_launch(void* const* d_in, const int* in_sizes, int n_in,
                              void* d_out, int out_size, void* d_ws,
                              size_t ws_size, hipStream_t stream) {
  (void)in_sizes; (void)n_in; (void)out_size; (void)ws_size;
  const float* x  = (const float*)d_in[0];
  const float* Wq = (const float*)d_in[1];
  const float* Wk = (const float*)d_in[2];
  const float* Wv = (const float*)d_in[3];
  float* out = (float*)d_out;

  char* ws = (char*)d_ws;
  const size_t MB = 1024 * 1024;
  bf16_t* xb  = (bf16_t*)(ws + 0 * MB);    // 16 MB  x bf16 [8192,1024]
  bf16_t* qb  = (bf16_t*)(ws + 16 * MB);   // 16 MB  q bf16 [8192,1024]
  bf16_t* kb  = (bf16_t*)(ws + 32 * MB);   // 16 MB  k bf16 [8192,1024]
  bf16_t* vtb = (bf16_t*)(ws + 48 * MB);   // 16 MB  v^T bf16 [1024,8192]
  bf16_t* wqb = (bf16_t*)(ws + 64 * MB);   // 2 MB
  bf16_t* wkb = (bf16_t*)(ws + 66 * MB);   // 2 MB
  bf16_t* wvb = (bf16_t*)(ws + 68 * MB);   // 2 MB
  bf16_t* Sb  = (bf16_t*)(ws + 70 * MB);   // 128 MB scores/P bf16 [8192,8192]
  // total: 198 MB

  cvt_kernel<<<8192, 256, 0, stream>>>(x, xb, 8192 * 1024);
  cvt_kernel<<<1024, 256, 0, stream>>>(Wq, wqb, 1024 * 1024);
  cvt_kernel<<<1024, 256, 0, stream>>>(Wk, wkb, 1024 * 1024);
  cvt_kernel<<<1024, 256, 0, stream>>>(Wv, wvb, 1024 * 1024);

  // q = x Wq^T, k = x Wk^T   [8192,1024]
  gemm_nt_kernel<1><<<dim3(8, 64), 256, 0, stream>>>(xb, wqb, qb, 8192, 1024, 1024, 1.0f);
  gemm_nt_kernel<1><<<dim3(8, 64), 256, 0, stream>>>(xb, wkb, kb, 8192, 1024, 1024, 1.0f);
  // v^T = Wv x^T   [1024,8192]
  gemm_nt_kernel<1><<<dim3(64, 8), 256, 0, stream>>>(wvb, xb, vtb, 1024, 8192, 1024, 1.0f);
  // S = (q k^T) / 8192   [8192,8192]
  gemm_nt_kernel<1><<<dim3(64, 64), 256, 0, stream>>>(qb, kb, Sb, 8192, 8192, 1024,
                                                      1.0f / 8192.0f);
  // P = softmax rows (in place, normalized)
  softmax_kernel<<<8192, 256, 0, stream>>>(Sb);
  // out = P v = P (v^T)^T   [8192,1024] fp32
  gemm_nt_kernel<0><<<dim3(8, 64), 256, 0, stream>>>(Sb, vtb, out, 8192, 1024, 8192,
                                                     1.0f);
}